// Round 1
// baseline (719.022 us; speedup 1.0000x reference)
//
#include <hip/hip_runtime.h>

#define NDm 4
#define Bm 128
#define Lm 200
#define Dm 512
#define NT (NDm*Bm*Lm)        // 102400 tokens
#define BM 32                 // tokens per block tile
#define NKB 16                // 512 / 32 k-blocks
#define LDA 40                // padded LDS row stride (ushorts): 80B rows, 16B-aligned
#define MAPPED_ELEMS ((size_t)NT * Dm)   // 52428800

typedef __attribute__((ext_vector_type(8))) short bf16x8;
typedef __attribute__((ext_vector_type(4))) float f32x4;

__device__ __forceinline__ unsigned short f2bf(float f) {
  unsigned int u = __float_as_uint(f);
  u += 0x7fffu + ((u >> 16) & 1u);   // round-to-nearest-even
  return (unsigned short)(u >> 16);
}

// ---- kernel 1: zero counters + convert W_maps to bf16, k-tile-major: [e][kb][n][kk]
__global__ __launch_bounds__(256) void prep_kernel(const float* __restrict__ W,
                                                   unsigned short* __restrict__ wbf,
                                                   int* __restrict__ counts) {
  int idx = blockIdx.x * 256 + threadIdx.x;       // over 4*512*512 = 1048576 exactly
  if (blockIdx.x == 0 && threadIdx.x < 8) counts[threadIdx.x] = 0;
  int k = idx & 511;
  int n = (idx >> 9) & 511;
  int j = idx >> 18;
  int kb = k >> 5, kk = k & 31;
  wbf[(((size_t)(j*NKB + kb))*Dm + n)*32 + kk] = f2bf(W[idx]);
}

// ---- kernel 2: bucket tokens by expert (bucket 4 = pad/label 0)
__global__ __launch_bounds__(256) void route_kernel(const int* __restrict__ lg,
                                                    int* __restrict__ counts,
                                                    int* __restrict__ lists) {
  int tt = blockIdx.x * 256 + threadIdx.x;        // grid 400*256 = NT exactly
  int i = tt / (Bm*Lm);
  int r = tt - i*(Bm*Lm);
  int b = r / Lm;
  int l = r - b*Lm;
  int lab = lg[(b*NDm + i)*Lm + l];               // lg_dom layout [B][ND][L]
  int bucket = (lab >= 1) ? (lab - 1) : 4;
  int lane = threadIdx.x & 63;
  int slot = 0;
  #pragma unroll
  for (int v = 0; v < 5; ++v) {                   // wave-aggregated atomics
    unsigned long long m = __ballot(bucket == v);
    if (m) {
      int leader = __ffsll((unsigned long long)m) - 1;
      int base = 0;
      if (lane == leader) base = atomicAdd(&counts[v], __popcll(m));
      base = __shfl(base, leader, 64);
      if (bucket == v)
        slot = base + __popcll(m & ((1ull << lane) - 1ull));
    }
  }
  lists[bucket*NT + slot] = tt;
}

// ---- kernel 3: grouped GEMM (BM tokens x 512) + bias + LayerNorm + pos/neg logits
__global__ __launch_bounds__(256) void moe_kernel(
    const float* __restrict__ logf, const float* __restrict__ bmaps,
    const float* __restrict__ emb, const float* __restrict__ gamma,
    const float* __restrict__ beta, const int* __restrict__ counts,
    const int* __restrict__ lists, const unsigned short* __restrict__ wbf,
    const int* __restrict__ posd, const int* __restrict__ negd,
    float* __restrict__ out) {
  __shared__ unsigned short Alds[BM * LDA];
  __shared__ unsigned short Wlds[Dm * LDA];
  __shared__ float reds[4][BM];
  __shared__ float redq[4][BM];
  __shared__ float mu_s[BM];
  __shared__ float rs_s[BM];
  __shared__ int tok_s[BM];
  __shared__ int pr_s[BM];
  __shared__ int nr_s[BM];

  const int e = blockIdx.y;                 // 0..3 experts, 4 = pad bucket
  const int cnt = counts[e];
  const int tile0 = blockIdx.x * BM;
  if (tile0 >= cnt) return;

  const int tid = threadIdx.x;
  const int wave = tid >> 6;
  const int lane = tid & 63;
  const int t = lane & 15;
  const int q = lane >> 4;

  // prolog: token ids + emb row ids for this tile
  if (tid < BM) {
    int idx = tile0 + tid;
    int tok = -1, pr = 0, nr = 0;
    if (idx < cnt) {
      tok = lists[e*NT + idx];
      int i = tok / (Bm*Lm);
      int r2 = tok - i*(Bm*Lm);
      int b = r2 / Lm;
      int l = r2 - b*Lm;
      int off = (b*NDm + i)*Lm + l;         // [B][ND][L] layout
      pr = posd[off];
      nr = negd[off];
    }
    tok_s[tid] = tok; pr_s[tid] = pr; nr_s[tid] = nr;
  }
  __syncthreads();

  f32x4 acc[2][8];
  #pragma unroll
  for (int mt = 0; mt < 2; ++mt)
    #pragma unroll
    for (int nt = 0; nt < 8; ++nt)
      acc[mt][nt] = (f32x4){0.f, 0.f, 0.f, 0.f};

  if (e < 4) {                              // pad bucket: acc stays 0
    const int arow = tid >> 3;              // 32 rows x 8 threads
    const int apart = tid & 7;
    const int atok = tok_s[arow];
    #pragma nounroll
    for (int kb = 0; kb < NKB; ++kb) {
      // stage A: fp32 -> bf16
      float4 av = make_float4(0.f, 0.f, 0.f, 0.f);
      if (atok >= 0)
        av = *(const float4*)(logf + (size_t)atok*Dm + kb*32 + apart*4);
      ushort4 ah;
      ah.x = f2bf(av.x); ah.y = f2bf(av.y); ah.z = f2bf(av.z); ah.w = f2bf(av.w);
      *(ushort4*)&Alds[arow*LDA + apart*4] = ah;
      // stage W: contiguous 32KB bf16 tile
      const unsigned short* wsrc = wbf + ((size_t)(e*NKB + kb)) * (Dm*32);
      #pragma unroll
      for (int u = 0; u < 8; ++u) {
        int eidx = (u*256 + tid) * 8;       // 16B chunk, lane-contiguous
        int n = eidx >> 5;
        int kk = eidx & 31;
        uint4 d = *(const uint4*)(wsrc + eidx);
        *(uint4*)&Wlds[n*LDA + kk] = d;
      }
      __syncthreads();
      bf16x8 af[2];
      #pragma unroll
      for (int mt = 0; mt < 2; ++mt)
        af[mt] = *(const bf16x8*)&Alds[(mt*16 + t)*LDA + q*8];
      bf16x8 bfr[8];
      #pragma unroll
      for (int nt = 0; nt < 8; ++nt)
        bfr[nt] = *(const bf16x8*)&Wlds[(wave*128 + nt*16 + t)*LDA + q*8];
      #pragma unroll
      for (int mt = 0; mt < 2; ++mt)
        #pragma unroll
        for (int nt = 0; nt < 8; ++nt)
          acc[mt][nt] = __builtin_amdgcn_mfma_f32_16x16x32_bf16(af[mt], bfr[nt], acc[mt][nt], 0, 0, 0);
      __syncthreads();
    }
  }

  // ---- epilogue: bias + LN stats
  const int wbase = wave * 128;
  float g[8], bb[8], bi[8];
  #pragma unroll
  for (int nt = 0; nt < 8; ++nt) {
    int n = wbase + nt*16 + t;
    g[nt]  = gamma[n];
    bb[nt] = beta[n];
    bi[nt] = (e < 4) ? bmaps[e*Dm + n] : 0.f;
  }
  #pragma unroll
  for (int mt = 0; mt < 2; ++mt) {
    #pragma unroll
    for (int r = 0; r < 4; ++r) {
      float s = 0.f, s2 = 0.f;
      #pragma unroll
      for (int nt = 0; nt < 8; ++nt) {
        float v = acc[mt][nt][r] + bi[nt];
        acc[mt][nt][r] = v;
        s += v; s2 += v*v;
      }
      #pragma unroll
      for (int d = 1; d < 16; d <<= 1) {
        s  += __shfl_xor(s, d, 64);
        s2 += __shfl_xor(s2, d, 64);
      }
      if (t == 0) {
        int m = mt*16 + q*4 + r;            // verified C/D layout: row=q*4+reg, col=t
        reds[wave][m] = s;
        redq[wave][m] = s2;
      }
    }
  }
  __syncthreads();
  if (tid < BM) {
    float S  = reds[0][tid] + reds[1][tid] + reds[2][tid] + reds[3][tid];
    float S2 = redq[0][tid] + redq[1][tid] + redq[2][tid] + redq[3][tid];
    float mu = S * (1.f/Dm);
    float var = fmaxf(S2 * (1.f/Dm) - mu*mu, 0.f);
    mu_s[tid] = mu;
    rs_s[tid] = rsqrtf(var + 1e-8f);
  }
  __syncthreads();

  // ---- normalize, write mapped, accumulate logits
  #pragma unroll
  for (int mt = 0; mt < 2; ++mt) {
    #pragma unroll
    for (int r = 0; r < 4; ++r) {
      int m = mt*16 + q*4 + r;
      float mu = mu_s[m];
      float rs = rs_s[m];
      int tok = tok_s[m];
      float pp = 0.f, nn = 0.f;
      if (tok >= 0) {
        const float* pe = emb + (size_t)pr_s[m]*Dm;
        const float* ne = emb + (size_t)nr_s[m]*Dm;
        float* od = out + (size_t)tok*Dm;
        #pragma unroll
        for (int nt = 0; nt < 8; ++nt) {
          int n = wbase + nt*16 + t;
          float val = (acc[mt][nt][r] - mu) * rs * g[nt] + bb[nt];
          od[n] = val;
          pp += val * pe[n];
          nn += val * ne[n];
        }
      }
      #pragma unroll
      for (int d = 1; d < 16; d <<= 1) {
        pp += __shfl_xor(pp, d, 64);
        nn += __shfl_xor(nn, d, 64);
      }
      if (t == 0) {
        reds[wave][m] = pp;
        redq[wave][m] = nn;
      }
    }
  }
  __syncthreads();
  if (tid < BM) {
    int tok = tok_s[tid];
    if (tok >= 0) {
      float P  = reds[0][tid] + reds[1][tid] + reds[2][tid] + reds[3][tid];
      float Nn = redq[0][tid] + redq[1][tid] + redq[2][tid] + redq[3][tid];
      out[MAPPED_ELEMS + tok] = P;
      out[MAPPED_ELEMS + NT + tok] = Nn;
    }
  }
}

extern "C" void kernel_launch(void* const* d_in, const int* in_sizes, int n_in,
                              void* d_out, int out_size, void* d_ws, size_t ws_size,
                              hipStream_t stream) {
  const float* logf  = (const float*)d_in[0];   // log_feats [ND,B,L,D]
  const float* Wm    = (const float*)d_in[1];   // W_maps [ND,D,D]
  const float* bm    = (const float*)d_in[2];   // b_maps [ND,D]
  const float* emb   = (const float*)d_in[3];   // emb_table [V,D]
  const float* gamma = (const float*)d_in[4];
  const float* beta  = (const float*)d_in[5];
  const int*   lg    = (const int*)d_in[6];     // lg_dom [B,ND,L]
  const int*   posd  = (const int*)d_in[7];     // pos_oth_dom [B,ND,L]
  const int*   negd  = (const int*)d_in[8];     // neg_oth_dom [B,ND,L]
  float* out = (float*)d_out;

  char* ws = (char*)d_ws;
  int* counts = (int*)ws;                               // 8 ints (+pad to 128B)
  int* lists  = (int*)(ws + 128);                       // 5*NT ints = 2,048,000 B
  unsigned short* wbf = (unsigned short*)(ws + 128 + (size_t)5*NT*4);  // 2 MB bf16 W

  prep_kernel<<<4096, 256, 0, stream>>>(Wm, wbf, counts);
  route_kernel<<<NT/256, 256, 0, stream>>>(lg, counts, lists);
  dim3 grid(NT/BM, 5);
  moe_kernel<<<grid, 256, 0, stream>>>(logf, bm, emb, gamma, beta,
                                       counts, lists, wbf, posd, negd, out);
}

// Round 2
// 671.733 us; speedup vs baseline: 1.0704x; 1.0704x over previous
//
#include <hip/hip_runtime.h>

#define NDm 4
#define Bm 128
#define Lm 200
#define Dm 512
#define NT (NDm*Bm*Lm)        // 102400 tokens
#define BM 32                 // tokens per block tile
#define NKB 16                // 512 / 32 k-blocks
#define ASTR 520              // ushort stride for A-tile rows (1040 B, 16B-aligned, bank-spread)
#define FSTR 516              // float stride for epilogue tile rows (2064 B, 16B-aligned)
#define MAPPED_ELEMS ((size_t)NT * Dm)   // 52428800

typedef __attribute__((ext_vector_type(8))) short bf16x8;
typedef __attribute__((ext_vector_type(4))) float f32x4;

__device__ __forceinline__ unsigned short f2bf(float f) {
  unsigned int u = __float_as_uint(f);
  u += 0x7fffu + ((u >> 16) & 1u);   // round-to-nearest-even
  return (unsigned short)(u >> 16);
}

// ---- kernel 1: zero counters + convert W_maps to bf16, k-tile-major: [e][kb][n][kk]
__global__ __launch_bounds__(256) void prep_kernel(const float* __restrict__ W,
                                                   unsigned short* __restrict__ wbf,
                                                   int* __restrict__ counts) {
  int idx = blockIdx.x * 256 + threadIdx.x;       // over 4*512*512 = 1048576 exactly
  if (blockIdx.x == 0 && threadIdx.x < 8) counts[threadIdx.x] = 0;
  int k = idx & 511;
  int n = (idx >> 9) & 511;
  int j = idx >> 18;
  int kb = k >> 5, kk = k & 31;
  wbf[(((size_t)(j*NKB + kb))*Dm + n)*32 + kk] = f2bf(W[idx]);
}

// ---- kernel 2: bucket tokens by expert (bucket 4 = pad/label 0)
__global__ __launch_bounds__(256) void route_kernel(const int* __restrict__ lg,
                                                    int* __restrict__ counts,
                                                    int* __restrict__ lists) {
  int tt = blockIdx.x * 256 + threadIdx.x;        // grid 400*256 = NT exactly
  int i = tt / (Bm*Lm);
  int r = tt - i*(Bm*Lm);
  int b = r / Lm;
  int l = r - b*Lm;
  int lab = lg[(b*NDm + i)*Lm + l];               // lg_dom layout [B][ND][L]
  int bucket = (lab >= 1) ? (lab - 1) : 4;
  int lane = threadIdx.x & 63;
  int slot = 0;
  #pragma unroll
  for (int v = 0; v < 5; ++v) {                   // wave-aggregated atomics
    unsigned long long m = __ballot(bucket == v);
    if (m) {
      int leader = __ffsll((unsigned long long)m) - 1;
      int base = 0;
      if (lane == leader) base = atomicAdd(&counts[v], __popcll(m));
      base = __shfl(base, leader, 64);
      if (bucket == v)
        slot = base + __popcll(m & ((1ull << lane) - 1ull));
    }
  }
  lists[bucket*NT + slot] = tt;
}

// ---- kernel 3: grouped GEMM (BM tokens x 512) + bias + LayerNorm + pos/neg logits
// A staged once to LDS (bf16); W (B-operand) loaded coalesced straight from L2;
// barrier-free K-loop; epilogue transposed through LDS for float4 global traffic.
__global__ __launch_bounds__(256, 3) void moe_kernel(
    const float* __restrict__ logf, const float* __restrict__ bmaps,
    const float* __restrict__ emb, const float* __restrict__ gamma,
    const float* __restrict__ beta, const int* __restrict__ counts,
    const int* __restrict__ lists, const unsigned short* __restrict__ wbf,
    const int* __restrict__ posd, const int* __restrict__ negd,
    float* __restrict__ out) {
  __shared__ __align__(16) unsigned char smem[BM * ASTR * 2];   // 33280 B, A-tile / epilogue union
  unsigned short* Alds = (unsigned short*)smem;                 // 32 rows x ASTR bf16
  float* Flds = (float*)smem;                                   // 16 rows x FSTR f32
  __shared__ float reds[4][16];
  __shared__ float redq[4][16];
  __shared__ float mu_s[16];
  __shared__ float rs_s[16];
  __shared__ int tok_s[BM];
  __shared__ int pr_s[BM];
  __shared__ int nr_s[BM];

  const int e = blockIdx.y;                 // 0..3 experts, 4 = pad bucket
  const int cnt = counts[e];
  const int tile0 = blockIdx.x * BM;
  if (tile0 >= cnt) return;

  const int tid = threadIdx.x;
  const int wave = tid >> 6;
  const int lane = tid & 63;
  const int t = lane & 15;
  const int q = lane >> 4;

  // prolog: token ids + emb row ids for this tile
  if (tid < BM) {
    int idx = tile0 + tid;
    int tok = -1, pr = 0, nr = 0;
    if (idx < cnt) {
      tok = lists[e*NT + idx];
      int i = tok / (Bm*Lm);
      int r2 = tok - i*(Bm*Lm);
      int b = r2 / Lm;
      int l = r2 - b*Lm;
      int off = (b*NDm + i)*Lm + l;         // [B][ND][L] layout
      pr = posd[off];
      nr = negd[off];
    }
    tok_s[tid] = tok; pr_s[tid] = pr; nr_s[tid] = nr;
  }
  __syncthreads();

  f32x4 acc[2][8];
  #pragma unroll
  for (int mt = 0; mt < 2; ++mt)
    #pragma unroll
    for (int nt = 0; nt < 8; ++nt)
      acc[mt][nt] = (f32x4){0.f, 0.f, 0.f, 0.f};

  if (e < 4) {                              // pad bucket: acc stays 0
    // ---- stage full A tile (32 tokens x 512) fp32->bf16, once
    const int arow = tid >> 3;              // 8 threads per row
    const int acol0 = (tid & 7) * 4;
    const int atok = tok_s[arow];
    const float* ap = logf + (size_t)(atok < 0 ? 0 : atok) * Dm;
    #pragma unroll 4
    for (int it = 0; it < 16; ++it) {
      int col = acol0 + it * 32;
      float4 av = make_float4(0.f, 0.f, 0.f, 0.f);
      if (atok >= 0) av = *(const float4*)(ap + col);
      ushort4 ah;
      ah.x = f2bf(av.x); ah.y = f2bf(av.y); ah.z = f2bf(av.z); ah.w = f2bf(av.w);
      *(ushort4*)&Alds[arow*ASTR + col] = ah;
    }
    __syncthreads();

    // ---- barrier-free K-loop: A from LDS, B coalesced from global (L2-resident)
    const unsigned short* pB = wbf + (size_t)e*(NKB*Dm*32)
                                   + (size_t)(wave*128 + t)*32 + q*8;
    const unsigned short* pA0 = &Alds[t*ASTR + q*8];
    #pragma unroll 2
    for (int kb = 0; kb < NKB; ++kb) {
      bf16x8 a0 = *(const bf16x8*)(pA0 + kb*32);
      bf16x8 a1 = *(const bf16x8*)(pA0 + 16*ASTR + kb*32);
      #pragma unroll
      for (int nt = 0; nt < 8; ++nt) {
        bf16x8 b = *(const bf16x8*)(pB + kb*(Dm*32) + nt*512);
        acc[0][nt] = __builtin_amdgcn_mfma_f32_16x16x32_bf16(a0, b, acc[0][nt], 0, 0, 0);
        acc[1][nt] = __builtin_amdgcn_mfma_f32_16x16x32_bf16(a1, b, acc[1][nt], 0, 0, 0);
      }
    }
  }
  __syncthreads();   // A-tile reads done; smem becomes epilogue buffer

  // per-lane bias (cols n = wave*128 + nt*16 + t), gamma/beta float4 chunks
  float bi[8];
  #pragma unroll
  for (int nt = 0; nt < 8; ++nt)
    bi[nt] = (e < 4) ? bmaps[e*Dm + wave*128 + nt*16 + t] : 0.f;
  float4 gm[2], bt[2];
  #pragma unroll
  for (int c = 0; c < 2; ++c) {
    int col = c*256 + lane*4;
    gm[c] = *(const float4*)(gamma + col);
    bt[c] = *(const float4*)(beta + col);
  }

  // ---- epilogue in two 16-row halves through LDS
  #pragma unroll
  for (int mt = 0; mt < 2; ++mt) {
    // pass 1: scatter acc(+bias) into Flds, accumulate LN partials
    #pragma unroll
    for (int r = 0; r < 4; ++r) {
      int row16 = q*4 + r;                  // verified C/D layout: row=q*4+reg, col=t
      float s = 0.f, s2 = 0.f;
      #pragma unroll
      for (int nt = 0; nt < 8; ++nt) {
        float v = acc[mt][nt][r] + bi[nt];
        Flds[row16*FSTR + wave*128 + nt*16 + t] = v;
        s += v; s2 += v*v;
      }
      #pragma unroll
      for (int d = 1; d < 16; d <<= 1) {
        s  += __shfl_xor(s, d, 64);
        s2 += __shfl_xor(s2, d, 64);
      }
      if (t == 0) { reds[wave][row16] = s; redq[wave][row16] = s2; }
    }
    __syncthreads();
    if (tid < 16) {
      float S  = reds[0][tid] + reds[1][tid] + reds[2][tid] + reds[3][tid];
      float S2 = redq[0][tid] + redq[1][tid] + redq[2][tid] + redq[3][tid];
      float mu = S * (1.f/Dm);
      float var = fmaxf(S2 * (1.f/Dm) - mu*mu, 0.f);
      mu_s[tid] = mu;
      rs_s[tid] = rsqrtf(var + 1e-8f);
    }
    __syncthreads();
    // pass 2: coalesced float4 normalize+store+logit dot; wave owns 4 rows
    #pragma unroll
    for (int rr = 0; rr < 4; ++rr) {
      int row16 = wave*4 + rr;
      int m = mt*16 + row16;
      int tok = tok_s[m];
      if (tok >= 0) {                       // wave-uniform branch
        float mu = mu_s[row16];
        float rs = rs_s[row16];
        const float* pe = emb + (size_t)pr_s[m]*Dm;
        const float* ne = emb + (size_t)nr_s[m]*Dm;
        float* od = out + (size_t)tok*Dm;
        float pp = 0.f, nn = 0.f;
        #pragma unroll
        for (int c = 0; c < 2; ++c) {
          int col = c*256 + lane*4;
          float4 v  = *(const float4*)&Flds[row16*FSTR + col];
          float4 p4 = *(const float4*)(pe + col);
          float4 n4 = *(const float4*)(ne + col);
          float4 o;
          o.x = (v.x - mu)*rs*gm[c].x + bt[c].x;
          o.y = (v.y - mu)*rs*gm[c].y + bt[c].y;
          o.z = (v.z - mu)*rs*gm[c].z + bt[c].z;
          o.w = (v.w - mu)*rs*gm[c].w + bt[c].w;
          *(float4*)(od + col) = o;
          pp += o.x*p4.x + o.y*p4.y + o.z*p4.z + o.w*p4.w;
          nn += o.x*n4.x + o.y*n4.y + o.z*n4.z + o.w*n4.w;
        }
        #pragma unroll
        for (int d = 1; d < 64; d <<= 1) {
          pp += __shfl_xor(pp, d, 64);
          nn += __shfl_xor(nn, d, 64);
        }
        if (lane == 0) {
          out[MAPPED_ELEMS + tok] = pp;
          out[MAPPED_ELEMS + NT + tok] = nn;
        }
      }
    }
    __syncthreads();
  }
}

extern "C" void kernel_launch(void* const* d_in, const int* in_sizes, int n_in,
                              void* d_out, int out_size, void* d_ws, size_t ws_size,
                              hipStream_t stream) {
  const float* logf  = (const float*)d_in[0];   // log_feats [ND,B,L,D]
  const float* Wm    = (const float*)d_in[1];   // W_maps [ND,D,D]
  const float* bm    = (const float*)d_in[2];   // b_maps [ND,D]
  const float* emb   = (const float*)d_in[3];   // emb_table [V,D]
  const float* gamma = (const float*)d_in[4];
  const float* beta  = (const float*)d_in[5];
  const int*   lg    = (const int*)d_in[6];     // lg_dom [B,ND,L]
  const int*   posd  = (const int*)d_in[7];     // pos_oth_dom [B,ND,L]
  const int*   negd  = (const int*)d_in[8];     // neg_oth_dom [B,ND,L]
  float* out = (float*)d_out;

  char* ws = (char*)d_ws;
  int* counts = (int*)ws;                               // 8 ints (+pad to 128B)
  int* lists  = (int*)(ws + 128);                       // 5*NT ints = 2,048,000 B
  unsigned short* wbf = (unsigned short*)(ws + 128 + (size_t)5*NT*4);  // 2 MB bf16 W

  prep_kernel<<<4096, 256, 0, stream>>>(Wm, wbf, counts);
  route_kernel<<<NT/256, 256, 0, stream>>>(lg, counts, lists);
  dim3 grid(NT/BM, 5);
  moe_kernel<<<grid, 256, 0, stream>>>(logf, bm, emb, gamma, beta,
                                       counts, lists, wbf, posd, negd, out);
}